// Round 9
// baseline (1403.321 us; speedup 1.0000x reference)
//
#include <hip/hip_runtime.h>
#include <stdint.h>

#define R_NODES 256
#define M_SAMP  512
#define S_STEPS 512
#define OUT_N   10

typedef unsigned int u32x2 __attribute__((ext_vector_type(2)));
typedef _Float16     half8 __attribute__((ext_vector_type(8)));
typedef float        f32x4 __attribute__((ext_vector_type(4)));

// ---------------- layout detection for bool inputs ----------------
// If bools were uploaded as int32, byte (4f+1) of every element is 0.
// If uploaded as uint8, ~half those bytes are 1.  flag=1 => uint8 layout.
__global__ void detect_layout(const uint8_t* __restrict__ x, int* __restrict__ flag) {
    __shared__ int any;
    if (threadIdx.x == 0) any = 0;
    __syncthreads();
    int acc = 0;
    for (int i = 0; i < 64; ++i)
        acc |= x[(size_t)(threadIdx.x * 64 + i) * 4 + 1];
    if (acc) atomicOr(&any, 1);
    __syncthreads();
    if (threadIdx.x == 0) *flag = any ? 1 : 0;
}

// ---------------- pack x bits: one uint32 per (m,s) ----------------
__global__ void pack_x(const uint8_t* __restrict__ x, const int* __restrict__ flag,
                       uint32_t* __restrict__ xp) {
    const int stride = (*flag) ? 1 : 4;
    const int f = blockIdx.x * blockDim.x + threadIdx.x;      // element idx, M*S*32 total
    const int val = x[(size_t)f * stride];
    const uint64_t mask = __ballot(val != 0);
    const int lane = threadIdx.x & 63;
    if ((lane & 31) == 0) {
        uint32_t w = (lane & 32) ? (uint32_t)(mask >> 32) : (uint32_t)mask;
        xp[f >> 5] = w;
    }
}

// ---------------- bit-pack the LUT: 256MB int32 -> 8MB bits ----------------
__device__ __forceinline__ uint32_t spread8(uint32_t x) {
    // bit i of low byte -> bit 4*i
    x = (x | (x << 12)) & 0x000F000Fu;
    x = (x | (x << 6))  & 0x03030303u;
    x = (x | (x << 3))  & 0x11111111u;
    return x;
}
__global__ void pack_lut(const int* __restrict__ lut, uint32_t* __restrict__ lp32) {
    const int lane = threadIdx.x & 63;
    const int gw = blockIdx.x * (blockDim.x >> 6) + (threadIdx.x >> 6); // 16384 waves
    const int4* src = (const int4*)lut;
    for (int it = 0; it < 16; ++it) {
        const int chunk = gw * 16 + it;                // 262144 wave-chunks total
        const int4 q = src[(size_t)chunk * 64 + lane]; // coalesced 16B/lane
        const uint64_t b0 = __ballot((q.x & 1) != 0);
        const uint64_t b1 = __ballot((q.y & 1) != 0);
        const uint64_t b2 = __ballot((q.z & 1) != 0);
        const uint64_t b3 = __ballot((q.w & 1) != 0);
        if (lane < 8) {
            const uint32_t B0 = (uint32_t)(b0 >> (8 * lane)) & 0xFF;
            const uint32_t B1 = (uint32_t)(b1 >> (8 * lane)) & 0xFF;
            const uint32_t B2 = (uint32_t)(b2 >> (8 * lane)) & 0xFF;
            const uint32_t B3 = (uint32_t)(b3 >> (8 * lane)) & 0xFF;
            const uint32_t w = spread8(B0) | (spread8(B1) << 1)
                             | (spread8(B2) << 2) | (spread8(B3) << 3);
            lp32[(size_t)chunk * 8 + lane] = w;
        }
    }
}

// ---------------- main reservoir scan: MFMA, 16 samples per block ----------
// idx[j][c] = sum_k primes[k]*W[j][k]*r[k][c] is EXACT in f16xf16+f32 MFMA:
// primes<=1619<2048 (f16-exact), r in {0,1}, sums <= 207246 < 2^24.
// 32 blocks x 512 threads (8 waves).  Wave w owns rows 32w..32w+31 as two
// 16x16x32 tiles; A-frags (W' = primes*W) live in 64 VGPRs for the whole
// kernel -> the per-step matvec reads NOTHING from L2 (R8's 2.18MB/step/XCD
// gather eliminated).  Per step: one barrier, 8 ds_read_b128 B-frags
// (16-sample state broadcast, double-buffered), 16 MFMA, 8 lp bit-lookups
// per lane (all in flight, one vmcnt(0)), input-injection folded into the
// producer, 2 ds_write_b64.  Layouts (m89-verified C: col=lane&15,
// row=(lane>>4)*4+reg; A/B: k=(lane>>4)*8+j, row/col=lane&15).
__global__ __launch_bounds__(512, 1) void reservoir_mfma(
    const uint32_t* __restrict__ xp, const uint64_t* __restrict__ lp,
    const int* __restrict__ input_nodes, const uint8_t* __restrict__ wres,
    const int* __restrict__ primes, const uint8_t* __restrict__ init_res,
    const int* __restrict__ flag, const float* __restrict__ rW,
    const float* __restrict__ rb, float* __restrict__ out)
{
    const int blk = blockIdx.x;
    const int t = threadIdx.x;          // 0..511
    const int l = t & 63;
    const int w = t >> 6;               // wave 0..7
    const int g = l >> 4;               // k-group 0..3
    const int c = l & 15;               // sample/col 0..15
    const int stride = (*flag) ? 1 : 4;

    __shared__ uint32_t sxp[S_STEPS * 16];     // [step][sample] input words, 32KB
    __shared__ _Float16 rf[2][16][264];        // state dbuf [sample][node], +8 pad

    // ---- stage this block's xp slice (consecutive t -> consecutive s) ----
    for (int i = t; i < 16 * S_STEPS; i += 512) {
        const int cc = i >> 9, ss = i & 511;
        sxp[ss * 16 + cc] = xp[(size_t)(blk * 16 + cc) * S_STEPS + ss];
    }

    // ---- A fragments: af[T][q][j] = W'[32w+16T+c][32q+8g+j] ----
    half8 af[2][8];
#pragma unroll
    for (int T = 0; T < 2; ++T) {
        const int row = 32 * w + 16 * T + c;
#pragma unroll
        for (int q = 0; q < 8; ++q) {
            half8 a;
#pragma unroll
            for (int j = 0; j < 8; ++j) {
                const int k = 32 * q + 8 * g + j;
                const int on = wres[(size_t)(row * 256 + k) * stride] ? 1 : 0;
                a[j] = (_Float16)(on ? (float)primes[k] : 0.f);
            }
            af[T][q] = a;
        }
    }

    // ---- producer nodes: nb0..nb0+3 (tile 0), nb1..nb1+3 (tile 1), sample c
    const int nb0 = 32 * w + 4 * g;
    const int nb1 = nb0 + 16;
    int slot0[4], slot1[4];
#pragma unroll
    for (int i = 0; i < 4; ++i) { slot0[i] = -1; slot1[i] = -1; }
    for (int i = 0; i < 32; ++i) {
        const int n = input_nodes[i];
#pragma unroll
        for (int j = 0; j < 4; ++j) {
            if (n == nb0 + j) slot0[j] = i;
            if (n == nb1 + j) slot1[j] = i;
        }
    }

    // ---- init state (init_res) into rf[0] ----
    {
        const int cs = t >> 5, h = t & 31;      // sample cs, nodes 8h..8h+7
        uint32_t pk[4];
#pragma unroll
        for (int p = 0; p < 4; ++p) {
            const int j0 = 8 * h + 2 * p;
            const uint32_t b0 = init_res[(size_t)j0 * stride] ? 1u : 0u;
            const uint32_t b1 = init_res[(size_t)(j0 + 1) * stride] ? 1u : 0u;
            pk[p] = b0 * 0x3C00u + b1 * 0x3C000000u;
        }
        *(uint4*)&rf[0][cs][8 * h] = make_uint4(pk[0], pk[1], pk[2], pk[3]);
    }
    __syncthreads();
    // inject x_0 (thread t -> slot t>>4, sample t&15)
    {
        const int sl = t >> 4, cc = t & 15;
        const int n = input_nodes[sl];
        const uint32_t bit = (sxp[cc] >> sl) & 1u;
        ((uint16_t*)&rf[0][cc][0])[n] = bit ? 0x3C00u : 0u;
    }
    __syncthreads();

    const uint64_t lpbase = (uint64_t)(uintptr_t)lp;
    int cur = 0;

    for (int s = 0; s < S_STEPS; ++s) {
        // ---- (1) B-frags from LDS + 16 MFMA ----
        const _Float16* br = &rf[cur][0][0];
        f32x4 acc0 = {0.f, 0.f, 0.f, 0.f}, acc1 = {0.f, 0.f, 0.f, 0.f};
#pragma unroll
        for (int q = 0; q < 8; ++q) {
            const half8 b = *(const half8*)(br + c * 264 + 32 * q + 8 * g);
            acc0 = __builtin_amdgcn_mfma_f32_16x16x32_f16(af[0][q], b, acc0, 0, 0, 0);
            acc1 = __builtin_amdgcn_mfma_f32_16x16x32_f16(af[1][q], b, acc1, 0, 0, 0);
        }

        // ---- (2) exact f32->u32 idx, 8 lp loads all in flight ----
        uint32_t i0[4], i1[4];
#pragma unroll
        for (int i = 0; i < 4; ++i) { i0[i] = (uint32_t)acc0[i]; i1[i] = (uint32_t)acc1[i]; }
        u32x2 d0[4], d1[4];
#pragma unroll
        for (int i = 0; i < 4; ++i) {
            const uint32_t o_ = ((uint32_t)(nb0 + i) << 15) + ((i0[i] >> 6) << 3);
            asm volatile("global_load_dwordx2 %0, %1, %2" : "=v"(d0[i]) : "v"(o_), "s"(lpbase));
        }
#pragma unroll
        for (int i = 0; i < 4; ++i) {
            const uint32_t o_ = ((uint32_t)(nb1 + i) << 15) + ((i1[i] >> 6) << 3);
            asm volatile("global_load_dwordx2 %0, %1, %2" : "=v"(d1[i]) : "v"(o_), "s"(lpbase));
        }
        const uint32_t xwn = sxp[((s + 1) & 511) * 16 + c];
        const int inj = (s + 1 < S_STEPS) ? 1 : 0;
        asm volatile("s_waitcnt vmcnt(0)");
        asm volatile("" : "+v"(d0[0]), "+v"(d0[1]), "+v"(d0[2]), "+v"(d0[3]),
                          "+v"(d1[0]), "+v"(d1[1]), "+v"(d1[2]), "+v"(d1[3]));

        // ---- (3) bits + folded input injection + pack f16 + write dbuf ----
        uint32_t b0[4], b1v[4];
#pragma unroll
        for (int i = 0; i < 4; ++i) {
            uint32_t bb = (uint32_t)(((((uint64_t)d0[i][1] << 32) | d0[i][0]) >> (i0[i] & 63)) & 1u);
            if (inj && slot0[i] >= 0) bb = (xwn >> slot0[i]) & 1u;
            b0[i] = bb;
            uint32_t b2 = (uint32_t)(((((uint64_t)d1[i][1] << 32) | d1[i][0]) >> (i1[i] & 63)) & 1u);
            if (inj && slot1[i] >= 0) b2 = (xwn >> slot1[i]) & 1u;
            b1v[i] = b2;
        }
        _Float16* bw = &rf[cur ^ 1][0][0];
        u32x2 p0, p1;
        p0[0] = b0[0]  * 0x3C00u + b0[1]  * 0x3C000000u;
        p0[1] = b0[2]  * 0x3C00u + b0[3]  * 0x3C000000u;
        p1[0] = b1v[0] * 0x3C00u + b1v[1] * 0x3C000000u;
        p1[1] = b1v[2] * 0x3C00u + b1v[3] * 0x3C000000u;
        *(u32x2*)(void*)(bw + c * 264 + nb0) = p0;
        *(u32x2*)(void*)(bw + c * 264 + nb1) = p1;
        __syncthreads();
        cur ^= 1;
    }

    // keep readout loads out of the main loop's schedule
    const float* rWo;
    const float* rbo;
    asm volatile("" : "=s"(rWo) : "0"(rW));
    asm volatile("" : "=s"(rbo) : "0"(rb));

    // readout: out[g][o] = b[o] + sum_j r[j]*W[o][j]; final state in rf[cur]
    const int cs = t >> 5, h = t & 31;
    float f[8];
#pragma unroll
    for (int j = 0; j < 8; ++j) f[j] = (float)rf[cur][cs][8 * h + j];
#pragma unroll
    for (int o = 0; o < OUT_N; ++o) {
        float accv = 0.f;
#pragma unroll
        for (int j = 0; j < 8; ++j) accv += f[j] * rWo[o * R_NODES + 8 * h + j];
        for (int off = 16; off > 0; off >>= 1)
            accv += __shfl_down(accv, off, 32);
        if (h == 0) out[(size_t)(blk * 16 + cs) * OUT_N + o] = accv + rbo[o];
    }
}

extern "C" void kernel_launch(void* const* d_in, const int* in_sizes, int n_in,
                              void* d_out, int out_size, void* d_ws, size_t ws_size,
                              hipStream_t stream) {
    const uint8_t* x        = (const uint8_t*)d_in[0];   // bool [M,S,D,B]
    const int* input_nodes  = (const int*)d_in[1];       // int32 [32]
    const int* lut          = (const int*)d_in[2];       // int32 [256, 2^18]
    const uint8_t* wres     = (const uint8_t*)d_in[3];   // bool [256,256]
    const int* primes       = (const int*)d_in[4];       // int32 [256]
    const uint8_t* init_res = (const uint8_t*)d_in[5];   // bool [256]
    const float* rW         = (const float*)d_in[6];     // f32 [10,256]
    const float* rb         = (const float*)d_in[7];     // f32 [10]
    float* out              = (float*)d_out;             // f32 [512,10]

    uint8_t* ws = (uint8_t*)d_ws;
    int*      flag = (int*)ws;                                        // 4 B
    uint32_t* xp   = (uint32_t*)(ws + 4096);                          // 1 MB
    uint64_t* lp   = (uint64_t*)(ws + 4096 + 1048576);                // 8 MB

    detect_layout<<<1, 256, 0, stream>>>(x, flag);
    pack_x<<<(M_SAMP * S_STEPS * 32) / 256, 256, 0, stream>>>(x, flag, xp);
    pack_lut<<<4096, 256, 0, stream>>>(lut, (uint32_t*)lp);
    reservoir_mfma<<<M_SAMP / 16, 512, 0, stream>>>(xp, lp, input_nodes, wres,
                                                    primes, init_res, flag,
                                                    rW, rb, out);
}

// Round 11
// 1060.541 us; speedup vs baseline: 1.3232x; 1.3232x over previous
//
#include <hip/hip_runtime.h>
#include <stdint.h>

#define R_NODES 256
#define M_SAMP  512
#define S_STEPS 512
#define OUT_N   10

// ---------------- layout detection for bool inputs ----------------
// If bools were uploaded as int32, byte (4f+1) of every element is 0.
// If uploaded as uint8, ~half those bytes are 1.  flag=1 => uint8 layout.
__global__ void detect_layout(const uint8_t* __restrict__ x, int* __restrict__ flag) {
    __shared__ int any;
    if (threadIdx.x == 0) any = 0;
    __syncthreads();
    int acc = 0;
    for (int i = 0; i < 64; ++i)
        acc |= x[(size_t)(threadIdx.x * 64 + i) * 4 + 1];
    if (acc) atomicOr(&any, 1);
    __syncthreads();
    if (threadIdx.x == 0) *flag = any ? 1 : 0;
}

// ---------------- pack x bits: one uint32 per (m,s) ----------------
__global__ void pack_x(const uint8_t* __restrict__ x, const int* __restrict__ flag,
                       uint32_t* __restrict__ xp) {
    const int stride = (*flag) ? 1 : 4;
    const int f = blockIdx.x * blockDim.x + threadIdx.x;      // element idx, M*S*32 total
    const int val = x[(size_t)f * stride];
    const uint64_t mask = __ballot(val != 0);
    const int lane = threadIdx.x & 63;
    if ((lane & 31) == 0) {
        uint32_t w = (lane & 32) ? (uint32_t)(mask >> 32) : (uint32_t)mask;
        xp[f >> 5] = w;
    }
}

// ---------------- bit-pack the LUT: 256MB int32 -> 8MB bits ----------------
__device__ __forceinline__ uint32_t spread8(uint32_t x) {
    // bit i of low byte -> bit 4*i
    x = (x | (x << 12)) & 0x000F000Fu;
    x = (x | (x << 6))  & 0x03030303u;
    x = (x | (x << 3))  & 0x11111111u;
    return x;
}
__global__ void pack_lut(const int* __restrict__ lut, uint32_t* __restrict__ lp32) {
    const int lane = threadIdx.x & 63;
    const int gw = blockIdx.x * (blockDim.x >> 6) + (threadIdx.x >> 6); // 16384 waves
    const int4* src = (const int4*)lut;
    for (int it = 0; it < 16; ++it) {
        const int chunk = gw * 16 + it;                // 262144 wave-chunks total
        const int4 q = src[(size_t)chunk * 64 + lane]; // coalesced 16B/lane
        const uint64_t b0 = __ballot((q.x & 1) != 0);
        const uint64_t b1 = __ballot((q.y & 1) != 0);
        const uint64_t b2 = __ballot((q.z & 1) != 0);
        const uint64_t b3 = __ballot((q.w & 1) != 0);
        if (lane < 8) {
            const uint32_t B0 = (uint32_t)(b0 >> (8 * lane)) & 0xFF;
            const uint32_t B1 = (uint32_t)(b1 >> (8 * lane)) & 0xFF;
            const uint32_t B2 = (uint32_t)(b2 >> (8 * lane)) & 0xFF;
            const uint32_t B3 = (uint32_t)(b3 >> (8 * lane)) & 0xFF;
            const uint32_t w = spread8(B0) | (spread8(B1) << 1)
                             | (spread8(B2) << 2) | (spread8(B3) << 3);
            lp32[(size_t)chunk * 8 + lane] = w;
        }
    }
}

// ---------------- main reservoir scan: bitplane popcount dot ---------------
// R8 lesson: table-gather has an L2-BW floor (2.18MB/step/XCD -> 2870cy).
// R9 lesson: MFMA -> 32 blocks, 3% occupancy: regressed.
// R10 lesson: v_dot4/v_sad builtins are not verifiably available on gfx950
// (possible compile failure).  This version uses ONLY guaranteed ops:
//   primes[k] < 2^11 -> 11 bit-planes.  Thread j holds PW[b][q] = 32-bit
//   words of plane b (bit k = W[j][k] AND prime-bit-b(k)): 88 VGPRs, built
//   once.  State = 256-bit mask R in LDS (8 words, broadcast, conflict-
//   free, double-buffered).  Per step: 8 LDS reads + 88 v_and + 88
//   accumulating v_bcnt (__popc) + 11 shift-adds -> EXACT idx < 2^18,
//   one lp bit-load (8MB table, L2-resident per R8), per-wave ballot,
//   ONE barrier.  512 blocks x 256 threads, 2 blocks/CU: co-resident
//   block hides lp latency + barrier.  VALU-bound target ~250us.
__global__ __launch_bounds__(256, 2) void reservoir_pop(
    const uint32_t* __restrict__ xp, const uint64_t* __restrict__ lp,
    const int* __restrict__ input_nodes, const uint8_t* __restrict__ wres,
    const int* __restrict__ primes, const uint8_t* __restrict__ init_res,
    const int* __restrict__ flag, const float* __restrict__ rW,
    const float* __restrict__ rb, float* __restrict__ out)
{
    const int m = blockIdx.x;
    const int j = threadIdx.x;          // node 0..255
    const int l = j & 63;
    const int w = j >> 6;               // wave 0..3
    const int stride = (*flag) ? 1 : 4;

    __shared__ uint32_t sxw[S_STEPS];   // 2KB input words
    __shared__ uint32_t rmask[2][8];    // 256-bit state dbuf, bit n = node n
    __shared__ float    lout[OUT_N];

    const uint32_t* xrow = xp + m * S_STEPS;
    for (int i = j; i < S_STEPS; i += 256) sxw[i] = xrow[i];

    int slot = -1;
    for (int i = 0; i < 32; ++i)
        if (input_nodes[i] == j) slot = i;

    // ---- build bit-planes (static indices only: b,q unrolled) ----
    uint32_t PW[11][8];
#pragma unroll
    for (int b = 0; b < 11; ++b)
#pragma unroll
        for (int q = 0; q < 8; ++q) PW[b][q] = 0;
#pragma unroll
    for (int q = 0; q < 8; ++q) {
        for (int bit = 0; bit < 32; ++bit) {
            const int k = 32 * q + bit;
            const uint32_t on = wres[(size_t)(j * 256 + k) * stride] ? 1u : 0u;
            const uint32_t p  = on * (uint32_t)primes[k];
#pragma unroll
            for (int b = 0; b < 11; ++b)
                PW[b][q] |= ((p >> b) & 1u) << bit;
        }
    }

    __syncthreads();                    // sxw ready
    // init state mask (init_res with x_0 injection folded)
    {
        int bv = init_res[(size_t)j * stride] ? 1 : 0;
        if (slot >= 0) bv = (sxw[0] >> slot) & 1;
        const uint64_t bal = __ballot(bv != 0);
        if (l == 0) {
            rmask[0][2 * w]     = (uint32_t)bal;
            rmask[0][2 * w + 1] = (uint32_t)(bal >> 32);
        }
    }
    __syncthreads();

    int cur = 0;
    int v = 0;
    for (int s = 0; s < S_STEPS; ++s) {
        const uint32_t R0 = rmask[cur][0], R1 = rmask[cur][1],
                       R2 = rmask[cur][2], R3 = rmask[cur][3],
                       R4 = rmask[cur][4], R5 = rmask[cur][5],
                       R6 = rmask[cur][6], R7 = rmask[cur][7];
        uint32_t idx = 0;
#pragma unroll
        for (int b = 0; b < 11; ++b) {
            uint32_t a;
            a  = (uint32_t)__popc(PW[b][0] & R0);
            a += (uint32_t)__popc(PW[b][1] & R1);
            a += (uint32_t)__popc(PW[b][2] & R2);
            a += (uint32_t)__popc(PW[b][3] & R3);
            a += (uint32_t)__popc(PW[b][4] & R4);
            a += (uint32_t)__popc(PW[b][5] & R5);
            a += (uint32_t)__popc(PW[b][6] & R6);
            a += (uint32_t)__popc(PW[b][7] & R7);
            idx += a << b;
        }

        // LUT bit lookup: lp row of node j = 2^18 bits = 4096 u64 (L2-hot)
        const uint64_t wv = lp[((size_t)j << 12) + (idx >> 6)];
        v = (int)((wv >> (idx & 63)) & 1);

        // next state bit with x_{s+1} injection folded (none after last)
        int wb = v;
        if (s + 1 < S_STEPS && slot >= 0) wb = (sxw[s + 1] >> slot) & 1;
        const uint64_t bal = __ballot(wb != 0);
        if (l == 0) {
            rmask[cur ^ 1][2 * w]     = (uint32_t)bal;
            rmask[cur ^ 1][2 * w + 1] = (uint32_t)(bal >> 32);
        }
        __syncthreads();
        cur ^= 1;
    }

    // readout: out[m][o] = b[o] + sum_j v_j * W[o][j]
    if (j < OUT_N) lout[j] = 0.f;
    __syncthreads();
#pragma unroll
    for (int o = 0; o < OUT_N; ++o) {
        float c = v ? rW[o * R_NODES + j] : 0.f;
        for (int off = 32; off > 0; off >>= 1)
            c += __shfl_down(c, off, 64);
        if (l == 0) atomicAdd(&lout[o], c);
    }
    __syncthreads();
    if (j < OUT_N) out[m * OUT_N + j] = lout[j] + rb[j];
}

extern "C" void kernel_launch(void* const* d_in, const int* in_sizes, int n_in,
                              void* d_out, int out_size, void* d_ws, size_t ws_size,
                              hipStream_t stream) {
    const uint8_t* x        = (const uint8_t*)d_in[0];   // bool [M,S,D,B]
    const int* input_nodes  = (const int*)d_in[1];       // int32 [32]
    const int* lut          = (const int*)d_in[2];       // int32 [256, 2^18]
    const uint8_t* wres     = (const uint8_t*)d_in[3];   // bool [256,256]
    const int* primes       = (const int*)d_in[4];       // int32 [256]
    const uint8_t* init_res = (const uint8_t*)d_in[5];   // bool [256]
    const float* rW         = (const float*)d_in[6];     // f32 [10,256]
    const float* rb         = (const float*)d_in[7];     // f32 [10]
    float* out              = (float*)d_out;             // f32 [512,10]

    uint8_t* ws = (uint8_t*)d_ws;
    int*      flag = (int*)ws;                                        // 4 B
    uint32_t* xp   = (uint32_t*)(ws + 4096);                          // 1 MB
    uint64_t* lp   = (uint64_t*)(ws + 4096 + 1048576);                // 8 MB

    detect_layout<<<1, 256, 0, stream>>>(x, flag);
    pack_x<<<(M_SAMP * S_STEPS * 32) / 256, 256, 0, stream>>>(x, flag, xp);
    pack_lut<<<4096, 256, 0, stream>>>(lut, (uint32_t*)lp);
    reservoir_pop<<<M_SAMP, 256, 0, stream>>>(xp, lp, input_nodes, wres,
                                              primes, init_res, flag,
                                              rW, rb, out);
}